// Round 4
// baseline (255.072 us; speedup 1.0000x reference)
//
#include <hip/hip_runtime.h>
#include <cstdint>
#include <cstddef>

// ---------------------------------------------------------------------------
// MultiHeadAttention forward, MI355X/gfx950.
// cvt(fp32->bf16) -> fused QKV GEMM (MFMA) -> flash attention -> out-proj.
// MFMA layouts (m89/m91/m120):
//   K=32 A-frag: lane l holds A[m=l&15][k=(l>>4)*8+j], j=0..7
//   K=32 B-frag: lane l holds Bt[n=l&15][k=(l>>4)*8+j]
//   K=16 A/B-frag: lane l holds X[.=l&15][k=(l>>4)*4+c], c=0..3
//   C/D: lane l, reg r holds D[m=(l>>4)*4+r][n=l&15]
// R3 attn restructure:
//  * 8 waves = 4 q-groups (32 q each) x 2 key-halves (64 keys) -> per-wave
//    LDS reads halve vs R3 (8KB K + 8KB V per wave-tile for 32q x 64k).
//  * S^T = MFMA16x16x32(K,Q) (C-layout: q = lr -> per-lane softmax stats).
//  * PV  = MFMA16x16x16(Vt, P): the 16x16 C-layout IS the K=16 B-operand
//    layout, so exp'd S^T packs to bf16x4 in registers -> NO LDS for P.
//  * O^T[d][q=lr]: alpha and 1/l are per-lane native (no shuffles).
//  * Epilogue: two key-half flash states merged via LDS, coalesced store.
// ---------------------------------------------------------------------------

#define D_MODEL 1024
#define NHEAD   16
#define HDIM    64
#define BATCH   2
#define SEQ     2048
#define BT      (BATCH * SEQ)   // 4096

typedef __bf16 bf16;
typedef __bf16 bf16x8 __attribute__((ext_vector_type(8)));
typedef __bf16 bf16x4 __attribute__((ext_vector_type(4)));
typedef float  floatx4 __attribute__((ext_vector_type(4)));
typedef short  short4v __attribute__((ext_vector_type(4)));

#define MFMA16(a, b, c) __builtin_amdgcn_mfma_f32_16x16x32_bf16((a), (b), (c), 0, 0, 0)

__device__ __forceinline__ floatx4 MFMA16B(bf16x4 a, bf16x4 b, floatx4 c) {
  return __builtin_amdgcn_mfma_f32_16x16x16bf16_1k(
      __builtin_bit_cast(short4v, a), __builtin_bit_cast(short4v, b), c, 0, 0, 0);
}

// async global->LDS, 16B per lane. LDS dest = wave-uniform base + lane*16.
__device__ __forceinline__ void async_cp16(const bf16* g, bf16* l) {
  __builtin_amdgcn_global_load_lds(
      (__attribute__((address_space(1))) void*)(g),
      (__attribute__((address_space(3))) void*)(l), 16, 0, 0);
}

// ---------------------------------------------------------------------------
// fp32 -> bf16 conversion for q,k,v and the 4 weight matrices.
// ---------------------------------------------------------------------------
__global__ __launch_bounds__(256) void cvt7(
    const float* __restrict__ s0, const float* __restrict__ s1,
    const float* __restrict__ s2, const float* __restrict__ s3,
    const float* __restrict__ s4, const float* __restrict__ s5,
    const float* __restrict__ s6,
    bf16* __restrict__ d0, bf16* __restrict__ d1, bf16* __restrict__ d2,
    bf16* __restrict__ d3, bf16* __restrict__ d4, bf16* __restrict__ d5,
    bf16* __restrict__ d6)
{
  const float* src; bf16* dst; int n4;
  switch (blockIdx.y) {
    case 0:  src = s0; dst = d0; n4 = (BT * D_MODEL) / 4; break;
    case 1:  src = s1; dst = d1; n4 = (BT * D_MODEL) / 4; break;
    case 2:  src = s2; dst = d2; n4 = (BT * D_MODEL) / 4; break;
    case 3:  src = s3; dst = d3; n4 = (D_MODEL * D_MODEL) / 4; break;
    case 4:  src = s4; dst = d4; n4 = (D_MODEL * D_MODEL) / 4; break;
    case 5:  src = s5; dst = d5; n4 = (D_MODEL * D_MODEL) / 4; break;
    default: src = s6; dst = d6; n4 = (D_MODEL * D_MODEL) / 4; break;
  }
  int stride = gridDim.x * blockDim.x;
  for (int i = blockIdx.x * blockDim.x + threadIdx.x; i < n4; i += stride) {
    float4 f = ((const float4*)src)[i];
    bf16x4 h;
    h[0] = (bf16)f.x; h[1] = (bf16)f.y; h[2] = (bf16)f.z; h[3] = (bf16)f.w;
    ((bf16x4*)dst)[i] = h;
  }
}

// ---------------------------------------------------------------------------
// 128x128-tile GEMM core, K=1024, BK=32 (m97 structure).
// ---------------------------------------------------------------------------
__device__ __forceinline__ void gemm128_core(
    const bf16* __restrict__ A, const bf16* __restrict__ W,
    int m0, int n0, bf16* As, bf16* Bs, floatx4 acc[4][4])
{
  const int t = threadIdx.x;
  const int l = t & 63, w = t >> 6;
  const int quad = l >> 4, lr = l & 15;
  const int wm = (w >> 1) * 64, wn = (w & 1) * 64;

  floatx4 z = {0.f, 0.f, 0.f, 0.f};
#pragma unroll
  for (int i = 0; i < 4; i++)
#pragma unroll
    for (int j = 0; j < 4; j++) acc[i][j] = z;

  for (int kt = 0; kt < 1024; kt += 32) {
    __syncthreads();
#pragma unroll
    for (int i = 0; i < 2; i++) {
      int c = i * 256 + t;
      int row = c >> 2, ci = c & 3;
      async_cp16(A + (size_t)(m0 + row) * 1024 + kt + ci * 8,
                 As + (i * 256 + w * 64) * 8);
      async_cp16(W + (size_t)(n0 + row) * 1024 + kt + ci * 8,
                 Bs + (i * 256 + w * 64) * 8);
    }
    __syncthreads();

    bf16x8 af[4], bfr[4];
#pragma unroll
    for (int i = 0; i < 4; i++) {
      af[i]  = *(const bf16x8*)(As + (wm + i * 16 + lr) * 32 + quad * 8);
      bfr[i] = *(const bf16x8*)(Bs + (wn + i * 16 + lr) * 32 + quad * 8);
    }
#pragma unroll
    for (int i = 0; i < 4; i++)
#pragma unroll
      for (int j = 0; j < 4; j++)
        acc[i][j] = MFMA16(af[i], bfr[j], acc[i][j]);
  }
}

// ---------------------------------------------------------------------------
// Fused QKV projection. zid selects (q,Wq)->qh, (k,Wk)->kh, (v,Wv)->vt.
// qh,kh: [B*H][T][64]; v stored TRANSPOSED [B*H][64][T].
// ---------------------------------------------------------------------------
__global__ __launch_bounds__(256) void qkv_gemm(
    const bf16* __restrict__ qb, const bf16* __restrict__ kb, const bf16* __restrict__ vb,
    const bf16* __restrict__ wq, const bf16* __restrict__ wk, const bf16* __restrict__ wv,
    const float* __restrict__ biasq, const float* __restrict__ biask, const float* __restrict__ biasv,
    bf16* __restrict__ qh, bf16* __restrict__ kh, bf16* __restrict__ vt)
{
  __shared__ bf16 As[128 * 32];
  __shared__ bf16 Bs[128 * 32];
  const int zid = blockIdx.z;
  const bf16* A = (zid == 0) ? qb : ((zid == 1) ? kb : vb);
  const bf16* W = (zid == 0) ? wq : ((zid == 1) ? wk : wv);
  const float* bias = (zid == 0) ? biasq : ((zid == 1) ? biask : biasv);
  const int m0 = blockIdx.x * 128, n0 = blockIdx.y * 128;

  floatx4 acc[4][4];
  gemm128_core(A, W, m0, n0, As, Bs, acc);

  const int t = threadIdx.x, l = t & 63, w = t >> 6;
  const int quad = l >> 4, lr = l & 15;
  const int wm = (w >> 1) * 64, wn = (w & 1) * 64;

  if (zid < 2) {
    bf16* out = (zid == 0) ? qh : kh;
#pragma unroll
    for (int i = 0; i < 4; i++) {
      int mbase = m0 + wm + i * 16 + quad * 4;       // global row (b*2048+t)
      int b  = mbase >> 11;
      int tq = mbase & 2047;
#pragma unroll
      for (int j = 0; j < 4; j++) {
        int n = n0 + wn + j * 16 + lr;               // e = h*64 + dh
        float bv = bias[n];
        int h = n >> 6, dh = n & 63;
        bf16* p = out + ((size_t)((b * NHEAD + h) * SEQ + tq)) * HDIM + dh;
#pragma unroll
        for (int r = 0; r < 4; r++)
          p[(size_t)r * HDIM] = (bf16)(acc[i][j][r] + bv);
      }
    }
  } else {
#pragma unroll
    for (int i = 0; i < 4; i++) {
      int mbase = m0 + wm + i * 16 + quad * 4;
      int b  = mbase >> 11;
      int tq = mbase & 2047;
#pragma unroll
      for (int j = 0; j < 4; j++) {
        int n = n0 + wn + j * 16 + lr;
        float bv = bias[n];
        int h = n >> 6, dh = n & 63;
        bf16x4 pk;
#pragma unroll
        for (int r = 0; r < 4; r++) pk[r] = (bf16)(acc[i][j][r] + bv);
        *(bf16x4*)(vt + ((size_t)((b * NHEAD + h) * HDIM + dh)) * SEQ + tq) = pk;
      }
    }
  }
}

// ---------------------------------------------------------------------------
// Flash attention, key-split. Grid (T/128, B*H), block 512 = 8 waves.
// wave w: q-group qsel = w&3 (rows qsel*32..+31), key-half = w>>2 (64 keys of
// each 128-key tile). Per tile: QK^T (16x16x32), per-lane softmax (q = lr),
// pack P to bf16x4, PV (16x16x16, P native in regs). Epilogue merges the two
// key-half states per q-group via LDS, then coalesced store.
// ---------------------------------------------------------------------------
__global__ __launch_bounds__(512, 4) void attn_fused(
    const bf16* __restrict__ qh, const bf16* __restrict__ kh,
    const bf16* __restrict__ vt, bf16* __restrict__ attn)
{
  // main loop: Ks [128][72] @0 (18432 B), Vts [64][136] @18432 (17408 B)
  // epilogue (after barrier): OB 32 tiles*1024B @0, stats @32768 (4 KB),
  //                           Ost [128][72] bf16 @36864 (18432 B)
  __shared__ __align__(16) char smem[55296];
  bf16* Ks  = (bf16*)smem;
  bf16* Vts = (bf16*)(smem + 18432);
  bf16* Ost = (bf16*)(smem + 36864);

  const int t = threadIdx.x, l = t & 63, w = t >> 6;   // w in 0..7
  const int quad = l >> 4, lr = l & 15;
  const int qsel = w & 3, half = w >> 2;
  const int bh = blockIdx.y;
  const int qt0 = blockIdx.x * 128;
  const bf16* qg = qh + (size_t)bh * SEQ * HDIM;
  const bf16* kg = kh + (size_t)bh * SEQ * HDIM;
  const bf16* vg = vt + (size_t)bh * HDIM * SEQ;

  // Q B-frags (K=32) for this wave's 32 q-rows: q = qt0 + qsel*32 + qt*16 + lr
  bf16x8 qf[2][2];
#pragma unroll
  for (int qt = 0; qt < 2; qt++)
#pragma unroll
    for (int ko = 0; ko < 2; ko++)
      qf[qt][ko] = *(const bf16x8*)(qg + (size_t)(qt0 + qsel * 32 + qt * 16 + lr) * HDIM
                                    + ko * 32 + quad * 8);

  floatx4 zz = {0.f, 0.f, 0.f, 0.f};
  floatx4 Oacc[4][2];   // O^T[d = dt*16+quad*4+r][q = qsel*32+qt*16+lr]
#pragma unroll
  for (int dt = 0; dt < 4; dt++)
#pragma unroll
    for (int qt = 0; qt < 2; qt++) Oacc[dt][qt] = zz;
  float mrow[2] = {-3.0e38f, -3.0e38f}, lrow[2] = {0.f, 0.f};
  const float scale = 0.125f;   // 1/sqrt(64)

  for (int kt0 = 0; kt0 < SEQ; kt0 += 128) {
    __syncthreads();
    // Stage K-tile [128][64] and V^T-tile [64][128], 16B chunks, 512 threads.
#pragma unroll
    for (int i = 0; i < 2; i++) {
      int c = t + 512 * i;
      { int row = c >> 3, ci = c & 7;   // K: 8 chunks/row
        *(int4*)(Ks + row * 72 + ci * 8) =
            *(const int4*)(kg + (size_t)(kt0 + row) * HDIM + ci * 8); }
      { int row = c >> 4, ci = c & 15;  // V^T: 16 chunks/row
        *(int4*)(Vts + row * 136 + ci * 8) =
            *(const int4*)(vg + (size_t)row * SEQ + kt0 + ci * 8); }
    }
    __syncthreads();

    // S^T tiles: s[kt][qt], lane holds S[q=lr][key = half*64 + kt*16 + quad*4 + r]
    floatx4 s[4][2];
#pragma unroll
    for (int kt = 0; kt < 4; kt++) {
      const bf16* krow = Ks + (half * 64 + kt * 16 + lr) * 72 + quad * 8;
      bf16x8 a0 = *(const bf16x8*)(krow);
      bf16x8 a1 = *(const bf16x8*)(krow + 32);
#pragma unroll
      for (int qt = 0; qt < 2; qt++) {
        floatx4 a = zz;
        a = MFMA16(a0, qf[qt][0], a);
        a = MFMA16(a1, qf[qt][1], a);
        s[kt][qt] = a;
      }
    }

    // Per-lane online softmax (q = lr native) + pack P to bf16x4.
    bf16x4 pk[4][2];
    float al[2];
#pragma unroll
    for (int qt = 0; qt < 2; qt++) {
      float rmax = s[0][qt][0];
#pragma unroll
      for (int kt = 0; kt < 4; kt++)
#pragma unroll
        for (int r = 0; r < 4; r++) rmax = fmaxf(rmax, s[kt][qt][r]);
      rmax = fmaxf(rmax, __shfl_xor(rmax, 16, 64));
      rmax = fmaxf(rmax, __shfl_xor(rmax, 32, 64));
      float mnew = fmaxf(mrow[qt], rmax * scale);
      al[qt] = __expf(mrow[qt] - mnew);
      mrow[qt] = mnew;
      float rsum = 0.f;
#pragma unroll
      for (int kt = 0; kt < 4; kt++)
#pragma unroll
        for (int r = 0; r < 4; r++) {
          float pv = __expf(s[kt][qt][r] * scale - mnew);
          rsum += pv;
          pk[kt][qt][r] = (bf16)pv;
        }
      rsum += __shfl_xor(rsum, 16, 64);
      rsum += __shfl_xor(rsum, 32, 64);
      lrow[qt] = lrow[qt] * al[qt] + rsum;
#pragma unroll
      for (int dt = 0; dt < 4; dt++)
#pragma unroll
        for (int r = 0; r < 4; r++) Oacc[dt][qt][r] *= al[qt];
    }

    // PV: O^T += MFMA_16x16x16(Vt_frag, P_frag). P is in regs (pk).
#pragma unroll
    for (int kt = 0; kt < 4; kt++)
#pragma unroll
      for (int dt = 0; dt < 4; dt++) {
        bf16x4 vf = *(const bf16x4*)(Vts + (dt * 16 + lr) * 136
                                     + half * 64 + kt * 16 + quad * 4);
#pragma unroll
        for (int qt = 0; qt < 2; qt++)
          Oacc[dt][qt] = MFMA16B(vf, pk[kt][qt], Oacc[dt][qt]);
      }
  }

  // ---- Epilogue: merge key-half states, normalize, store coalesced. ----
  __syncthreads();   // done reading Ks/Vts; smem is repurposed below

  if (half == 1) {
    // upper waves dump O^T tiles + (m,l) stats
#pragma unroll
    for (int qt = 0; qt < 2; qt++) {
#pragma unroll
      for (int dt = 0; dt < 4; dt++) {
        int tid = (qsel * 2 + qt) * 4 + dt;
        *(floatx4*)(smem + tid * 1024 + l * 16) = Oacc[dt][qt];
      }
      if (quad == 0)
        *(float2*)(smem + 32768 + ((qsel * 2 + qt) * 16 + lr) * 8) =
            make_float2(mrow[qt], lrow[qt]);
    }
  }
  __syncthreads();

  if (half == 0) {
#pragma unroll
    for (int qt = 0; qt < 2; qt++) {
      float2 st = *(const float2*)(smem + 32768 + ((qsel * 2 + qt) * 16 + lr) * 8);
      float ms = fmaxf(mrow[qt], st.x);
      float aA = __expf(mrow[qt] - ms);
      float aB = __expf(st.x - ms);
      float inv = 1.0f / (lrow[qt] * aA + st.y * aB);
      float fA = aA * inv, fB = aB * inv;
#pragma unroll
      for (int dt = 0; dt < 4; dt++) {
        int tid = (qsel * 2 + qt) * 4 + dt;
        floatx4 ob = *(const floatx4*)(smem + tid * 1024 + l * 16);
        int qloc = qsel * 32 + qt * 16 + lr;
        bf16x4 ov;
#pragma unroll
        for (int r = 0; r < 4; r++)
          ov[r] = (bf16)(Oacc[dt][qt][r] * fA + ob[r] * fB);
        *(bf16x4*)(Ost + qloc * 72 + dt * 16 + quad * 4) = ov;
      }
    }
  }
  __syncthreads();

  // stream Ost [128 q][64 d] to attn[b][qt0+row][h*64 + d], coalesced 16B.
  const int b = bh >> 4, h = bh & 15;
#pragma unroll
  for (int i = 0; i < 2; i++) {
    int c = t + 512 * i;
    int row = c >> 3, ci = c & 7;
    *(int4*)(attn + ((size_t)b * SEQ + qt0 + row) * D_MODEL + h * HDIM + ci * 8) =
        *(const int4*)(Ost + row * 72 + ci * 8);
  }
}

// ---------------------------------------------------------------------------
// Output projection: out = attn @ Wo^T + bo, fp32 output.
// ---------------------------------------------------------------------------
__global__ __launch_bounds__(256) void oproj_gemm(
    const bf16* __restrict__ attn, const bf16* __restrict__ wo,
    const float* __restrict__ bo, float* __restrict__ out)
{
  __shared__ bf16 As[128 * 32];
  __shared__ bf16 Bs[128 * 32];
  const int m0 = blockIdx.x * 128, n0 = blockIdx.y * 128;

  floatx4 acc[4][4];
  gemm128_core(attn, wo, m0, n0, As, Bs, acc);

  const int t = threadIdx.x, l = t & 63, w = t >> 6;
  const int quad = l >> 4, lr = l & 15;
  const int wm = (w >> 1) * 64, wn = (w & 1) * 64;

#pragma unroll
  for (int i = 0; i < 4; i++) {
    int m = m0 + wm + i * 16 + quad * 4;
#pragma unroll
    for (int j = 0; j < 4; j++) {
      int n = n0 + wn + j * 16 + lr;
      float bv = bo[n];
      float* p = out + (size_t)m * D_MODEL + n;
#pragma unroll
      for (int r = 0; r < 4; r++)
        p[(size_t)r * D_MODEL] = acc[i][j][r] + bv;
    }
  }
}

// ---------------------------------------------------------------------------
extern "C" void kernel_launch(void* const* d_in, const int* in_sizes, int n_in,
                              void* d_out, int out_size, void* d_ws, size_t ws_size,
                              hipStream_t stream)
{
  const float* q  = (const float*)d_in[0];
  const float* k  = (const float*)d_in[1];
  const float* v  = (const float*)d_in[2];
  const float* Wq = (const float*)d_in[3];
  const float* bq = (const float*)d_in[4];
  const float* Wk = (const float*)d_in[5];
  const float* bk = (const float*)d_in[6];
  const float* Wv = (const float*)d_in[7];
  const float* bv = (const float*)d_in[8];
  const float* Wo = (const float*)d_in[9];
  const float* bo = (const float*)d_in[10];

  const size_t NQ = (size_t)BT * D_MODEL;        // 4194304
  const size_t NW = (size_t)D_MODEL * D_MODEL;   // 1048576

  bf16* p = (bf16*)d_ws;
  bf16* qb   = p; p += NQ;
  bf16* kb   = p; p += NQ;
  bf16* vb   = p; p += NQ;
  bf16* wqb  = p; p += NW;
  bf16* wkb  = p; p += NW;
  bf16* wvb  = p; p += NW;
  bf16* wob  = p; p += NW;
  bf16* qhp  = p; p += NQ;   // [B*H][T][64]
  bf16* khp  = p; p += NQ;   // [B*H][T][64]
  bf16* vtp  = p; p += NQ;   // [B*H][64][T]
  bf16* attn = p; p += NQ;   // [B][T][1024]

  cvt7<<<dim3(1024, 7, 1), 256, 0, stream>>>(q, k, v, Wq, Wk, Wv, Wo,
                                             qb, kb, vb, wqb, wkb, wvb, wob);
  qkv_gemm<<<dim3(32, 8, 3), 256, 0, stream>>>(qb, kb, vb, wqb, wkb, wvb,
                                               bq, bk, bv, qhp, khp, vtp);
  attn_fused<<<dim3(16, 32, 1), 512, 0, stream>>>(qhp, khp, vtp, attn);
  oproj_gemm<<<dim3(32, 8, 1), 256, 0, stream>>>(attn, wob, bo, (float*)d_out);
}

// Round 5
// 238.598 us; speedup vs baseline: 1.0690x; 1.0690x over previous
//
#include <hip/hip_runtime.h>
#include <cstdint>
#include <cstddef>

// ---------------------------------------------------------------------------
// MultiHeadAttention forward, MI355X/gfx950.
// cvt(fp32->bf16) -> fused QKV GEMM (MFMA) -> flash attention -> out-proj.
// MFMA layouts (m89/m91/m120):
//   K=32 A-frag: lane l holds A[m=l&15][k=(l>>4)*8+j], j=0..7
//   K=32 B-frag: lane l holds Bt[n=l&15][k=(l>>4)*8+j]
//   K=16 A/B-frag: lane l holds X[.=l&15][k=(l>>4)*4+c], c=0..3
//   C/D: lane l, reg r holds D[m=(l>>4)*4+r][n=l&15]
// R5 attn: R3 wave assignment (8 waves x 16 q-rows, all 128 keys/wave -> no
// cross-wave merge) + R4's in-register PV: 16x16 C-layout == K=16 B-operand
// layout, so exp'd S^T (pk, bf16x4) feeds v_mfma_f32_16x16x16_bf16 directly.
// No Pbuf LDS round-trip, no alpha shuffles; O^T[d][q=lr] per-lane stats.
// Register budget ~85 (< 128 cap at launch_bounds(512,4)) -> no scratch
// spills (R4's 22 MB WRITE_SIZE regression).
// ---------------------------------------------------------------------------

#define D_MODEL 1024
#define NHEAD   16
#define HDIM    64
#define BATCH   2
#define SEQ     2048
#define BT      (BATCH * SEQ)   // 4096

typedef __bf16 bf16;
typedef __bf16 bf16x8 __attribute__((ext_vector_type(8)));
typedef __bf16 bf16x4 __attribute__((ext_vector_type(4)));
typedef float  floatx4 __attribute__((ext_vector_type(4)));
typedef short  short4v __attribute__((ext_vector_type(4)));

#define MFMA16(a, b, c) __builtin_amdgcn_mfma_f32_16x16x32_bf16((a), (b), (c), 0, 0, 0)

__device__ __forceinline__ floatx4 MFMA16B(bf16x4 a, bf16x4 b, floatx4 c) {
  return __builtin_amdgcn_mfma_f32_16x16x16bf16_1k(
      __builtin_bit_cast(short4v, a), __builtin_bit_cast(short4v, b), c, 0, 0, 0);
}

// async global->LDS, 16B per lane. LDS dest = wave-uniform base + lane*16.
__device__ __forceinline__ void async_cp16(const bf16* g, bf16* l) {
  __builtin_amdgcn_global_load_lds(
      (__attribute__((address_space(1))) void*)(g),
      (__attribute__((address_space(3))) void*)(l), 16, 0, 0);
}

// ---------------------------------------------------------------------------
// fp32 -> bf16 conversion for q,k,v and the 4 weight matrices.
// ---------------------------------------------------------------------------
__global__ __launch_bounds__(256) void cvt7(
    const float* __restrict__ s0, const float* __restrict__ s1,
    const float* __restrict__ s2, const float* __restrict__ s3,
    const float* __restrict__ s4, const float* __restrict__ s5,
    const float* __restrict__ s6,
    bf16* __restrict__ d0, bf16* __restrict__ d1, bf16* __restrict__ d2,
    bf16* __restrict__ d3, bf16* __restrict__ d4, bf16* __restrict__ d5,
    bf16* __restrict__ d6)
{
  const float* src; bf16* dst; int n4;
  switch (blockIdx.y) {
    case 0:  src = s0; dst = d0; n4 = (BT * D_MODEL) / 4; break;
    case 1:  src = s1; dst = d1; n4 = (BT * D_MODEL) / 4; break;
    case 2:  src = s2; dst = d2; n4 = (BT * D_MODEL) / 4; break;
    case 3:  src = s3; dst = d3; n4 = (D_MODEL * D_MODEL) / 4; break;
    case 4:  src = s4; dst = d4; n4 = (D_MODEL * D_MODEL) / 4; break;
    case 5:  src = s5; dst = d5; n4 = (D_MODEL * D_MODEL) / 4; break;
    default: src = s6; dst = d6; n4 = (D_MODEL * D_MODEL) / 4; break;
  }
  int stride = gridDim.x * blockDim.x;
  for (int i = blockIdx.x * blockDim.x + threadIdx.x; i < n4; i += stride) {
    float4 f = ((const float4*)src)[i];
    bf16x4 h;
    h[0] = (bf16)f.x; h[1] = (bf16)f.y; h[2] = (bf16)f.z; h[3] = (bf16)f.w;
    ((bf16x4*)dst)[i] = h;
  }
}

// ---------------------------------------------------------------------------
// 128x128-tile GEMM core, K=1024, BK=32 (m97 structure).
// ---------------------------------------------------------------------------
__device__ __forceinline__ void gemm128_core(
    const bf16* __restrict__ A, const bf16* __restrict__ W,
    int m0, int n0, bf16* As, bf16* Bs, floatx4 acc[4][4])
{
  const int t = threadIdx.x;
  const int l = t & 63, w = t >> 6;
  const int quad = l >> 4, lr = l & 15;
  const int wm = (w >> 1) * 64, wn = (w & 1) * 64;

  floatx4 z = {0.f, 0.f, 0.f, 0.f};
#pragma unroll
  for (int i = 0; i < 4; i++)
#pragma unroll
    for (int j = 0; j < 4; j++) acc[i][j] = z;

  for (int kt = 0; kt < 1024; kt += 32) {
    __syncthreads();
#pragma unroll
    for (int i = 0; i < 2; i++) {
      int c = i * 256 + t;
      int row = c >> 2, ci = c & 3;
      async_cp16(A + (size_t)(m0 + row) * 1024 + kt + ci * 8,
                 As + (i * 256 + w * 64) * 8);
      async_cp16(W + (size_t)(n0 + row) * 1024 + kt + ci * 8,
                 Bs + (i * 256 + w * 64) * 8);
    }
    __syncthreads();

    bf16x8 af[4], bfr[4];
#pragma unroll
    for (int i = 0; i < 4; i++) {
      af[i]  = *(const bf16x8*)(As + (wm + i * 16 + lr) * 32 + quad * 8);
      bfr[i] = *(const bf16x8*)(Bs + (wn + i * 16 + lr) * 32 + quad * 8);
    }
#pragma unroll
    for (int i = 0; i < 4; i++)
#pragma unroll
      for (int j = 0; j < 4; j++)
        acc[i][j] = MFMA16(af[i], bfr[j], acc[i][j]);
  }
}

// ---------------------------------------------------------------------------
// Fused QKV projection. zid selects (q,Wq)->qh, (k,Wk)->kh, (v,Wv)->vt.
// qh,kh: [B*H][T][64]; v stored TRANSPOSED [B*H][64][T].
// ---------------------------------------------------------------------------
__global__ __launch_bounds__(256) void qkv_gemm(
    const bf16* __restrict__ qb, const bf16* __restrict__ kb, const bf16* __restrict__ vb,
    const bf16* __restrict__ wq, const bf16* __restrict__ wk, const bf16* __restrict__ wv,
    const float* __restrict__ biasq, const float* __restrict__ biask, const float* __restrict__ biasv,
    bf16* __restrict__ qh, bf16* __restrict__ kh, bf16* __restrict__ vt)
{
  __shared__ bf16 As[128 * 32];
  __shared__ bf16 Bs[128 * 32];
  const int zid = blockIdx.z;
  const bf16* A = (zid == 0) ? qb : ((zid == 1) ? kb : vb);
  const bf16* W = (zid == 0) ? wq : ((zid == 1) ? wk : wv);
  const float* bias = (zid == 0) ? biasq : ((zid == 1) ? biask : biasv);
  const int m0 = blockIdx.x * 128, n0 = blockIdx.y * 128;

  floatx4 acc[4][4];
  gemm128_core(A, W, m0, n0, As, Bs, acc);

  const int t = threadIdx.x, l = t & 63, w = t >> 6;
  const int quad = l >> 4, lr = l & 15;
  const int wm = (w >> 1) * 64, wn = (w & 1) * 64;

  if (zid < 2) {
    bf16* out = (zid == 0) ? qh : kh;
#pragma unroll
    for (int i = 0; i < 4; i++) {
      int mbase = m0 + wm + i * 16 + quad * 4;       // global row (b*2048+t)
      int b  = mbase >> 11;
      int tq = mbase & 2047;
#pragma unroll
      for (int j = 0; j < 4; j++) {
        int n = n0 + wn + j * 16 + lr;               // e = h*64 + dh
        float bv = bias[n];
        int h = n >> 6, dh = n & 63;
        bf16* p = out + ((size_t)((b * NHEAD + h) * SEQ + tq)) * HDIM + dh;
#pragma unroll
        for (int r = 0; r < 4; r++)
          p[(size_t)r * HDIM] = (bf16)(acc[i][j][r] + bv);
      }
    }
  } else {
#pragma unroll
    for (int i = 0; i < 4; i++) {
      int mbase = m0 + wm + i * 16 + quad * 4;
      int b  = mbase >> 11;
      int tq = mbase & 2047;
#pragma unroll
      for (int j = 0; j < 4; j++) {
        int n = n0 + wn + j * 16 + lr;
        float bv = bias[n];
        int h = n >> 6, dh = n & 63;
        bf16x4 pk;
#pragma unroll
        for (int r = 0; r < 4; r++) pk[r] = (bf16)(acc[i][j][r] + bv);
        *(bf16x4*)(vt + ((size_t)((b * NHEAD + h) * HDIM + dh)) * SEQ + tq) = pk;
      }
    }
  }
}

// ---------------------------------------------------------------------------
// Flash attention. Grid (T/128, B*H), block 512 = 8 waves; wave w owns
// q-rows qt0 + w*16 + lr, all 128 keys of each tile (no state merge).
// Per 128-key tile:
//   S^T tiles (8x): MFMA16x16x32(K_frag, Q_frag); lane holds
//     S[q=lr][key = ni*16 + quad*4 + r] -> per-lane softmax stats.
//   exp -> pk[8] bf16x4 (C-layout == K=16 B-operand layout).
//   PV: O^T[d][q=lr] += MFMA16x16x16(Vt_frag, pk) -- P never leaves regs.
// Epilogue: normalize per-lane, transpose via LDS (Ks overlay), coalesced
// 16B stores.
// ---------------------------------------------------------------------------
__global__ __launch_bounds__(512, 4) void attn_fused(
    const bf16* __restrict__ qh, const bf16* __restrict__ kh,
    const bf16* __restrict__ vt, bf16* __restrict__ attn)
{
  __shared__ __align__(16) char smem[35840];
  bf16* Ks  = (bf16*)smem;            // [128][72], 18432 B
  bf16* Vts = (bf16*)(smem + 18432);  // [64][136], 17408 B
  bf16* Ost = (bf16*)smem;            // epilogue overlay [128][72]

  const int t = threadIdx.x, l = t & 63, w = t >> 6;   // w in 0..7
  const int quad = l >> 4, lr = l & 15;
  const int bh = blockIdx.y;
  const int qt0 = blockIdx.x * 128;
  const bf16* qg = qh + (size_t)bh * SEQ * HDIM;
  const bf16* kg = kh + (size_t)bh * SEQ * HDIM;
  const bf16* vg = vt + (size_t)bh * HDIM * SEQ;

  // Q B-frags (K=32) for this wave's 16 q-rows: q = qt0 + w*16 + lr.
  bf16x8 qf[2];
#pragma unroll
  for (int ko = 0; ko < 2; ko++)
    qf[ko] = *(const bf16x8*)(qg + (size_t)(qt0 + w * 16 + lr) * HDIM
                              + ko * 32 + quad * 8);

  floatx4 zz = {0.f, 0.f, 0.f, 0.f};
  floatx4 Oacc[4];   // O^T[d = dt*16 + quad*4 + r][q = lr]
#pragma unroll
  for (int dt = 0; dt < 4; dt++) Oacc[dt] = zz;
  float mrow = -3.0e38f, lrow = 0.f;
  const float scale = 0.125f;   // 1/sqrt(64)

  for (int kt0 = 0; kt0 < SEQ; kt0 += 128) {
    __syncthreads();
    // Stage K-tile [128][64] and V^T-tile [64][128], 16B chunks, 512 threads.
#pragma unroll
    for (int i = 0; i < 2; i++) {
      int c = t + 512 * i;
      { int row = c >> 3, ci = c & 7;   // K: 8 chunks/row
        *(int4*)(Ks + row * 72 + ci * 8) =
            *(const int4*)(kg + (size_t)(kt0 + row) * HDIM + ci * 8); }
      { int row = c >> 4, ci = c & 15;  // V^T: 16 chunks/row
        *(int4*)(Vts + row * 136 + ci * 8) =
            *(const int4*)(vg + (size_t)row * SEQ + kt0 + ci * 8); }
    }
    __syncthreads();

    // S^T: lane holds S[q=lr][key = ni*16 + quad*4 + r], ni=0..7.
    floatx4 s[8];
#pragma unroll
    for (int ni = 0; ni < 8; ni++) {
      const bf16* krow = Ks + (ni * 16 + lr) * 72 + quad * 8;
      bf16x8 k0 = *(const bf16x8*)(krow);
      bf16x8 k1 = *(const bf16x8*)(krow + 32);
      floatx4 a = zz;
      a = MFMA16(k0, qf[0], a);
      a = MFMA16(k1, qf[1], a);
      s[ni] = a;
    }

    // Per-lane online softmax (q = lr; reduce over the 4 quad-lanes).
    float rmax = s[0][0];
#pragma unroll
    for (int ni = 0; ni < 8; ni++)
#pragma unroll
      for (int r = 0; r < 4; r++) rmax = fmaxf(rmax, s[ni][r]);
    rmax = fmaxf(rmax, __shfl_xor(rmax, 16, 64));
    rmax = fmaxf(rmax, __shfl_xor(rmax, 32, 64));
    float mnew = fmaxf(mrow, rmax * scale);
    float al = __expf(mrow - mnew);
    mrow = mnew;

    bf16x4 pk[8];
    float rsum = 0.f;
#pragma unroll
    for (int ni = 0; ni < 8; ni++)
#pragma unroll
      for (int r = 0; r < 4; r++) {
        float pv = __expf(s[ni][r] * scale - mnew);
        rsum += pv;
        pk[ni][r] = (bf16)pv;
      }
    rsum += __shfl_xor(rsum, 16, 64);
    rsum += __shfl_xor(rsum, 32, 64);
    lrow = lrow * al + rsum;
#pragma unroll
    for (int dt = 0; dt < 4; dt++)
#pragma unroll
      for (int r = 0; r < 4; r++) Oacc[dt][r] *= al;

    // PV: O^T += MFMA_16x16x16(Vt_frag, P_frag); P is in regs (pk).
#pragma unroll
    for (int ni = 0; ni < 8; ni++)
#pragma unroll
      for (int dt = 0; dt < 4; dt++) {
        bf16x4 vf = *(const bf16x4*)(Vts + (dt * 16 + lr) * 136
                                     + ni * 16 + quad * 4);
        Oacc[dt] = MFMA16B(vf, pk[ni], Oacc[dt]);
      }
  }

  // ---- Epilogue: normalize, transpose via LDS, coalesced store. ----
  float inv = 1.0f / lrow;
  __syncthreads();   // done with Ks/Vts; overlay Ost
#pragma unroll
  for (int dt = 0; dt < 4; dt++) {
    bf16x4 ov;
#pragma unroll
    for (int r = 0; r < 4; r++) ov[r] = (bf16)(Oacc[dt][r] * inv);
    *(bf16x4*)(Ost + (size_t)(w * 16 + lr) * 72 + dt * 16 + quad * 4) = ov;
  }
  __syncthreads();

  // stream Ost [128 q][64 d] to attn[b][qt0+row][h*64 + d], coalesced 16B.
  const int b = bh >> 4, h = bh & 15;
#pragma unroll
  for (int i = 0; i < 2; i++) {
    int c = t + 512 * i;
    int row = c >> 3, ci = c & 7;
    *(int4*)(attn + ((size_t)b * SEQ + qt0 + row) * D_MODEL + h * HDIM + ci * 8) =
        *(const int4*)(Ost + row * 72 + ci * 8);
  }
}

// ---------------------------------------------------------------------------
// Output projection: out = attn @ Wo^T + bo, fp32 output.
// ---------------------------------------------------------------------------
__global__ __launch_bounds__(256) void oproj_gemm(
    const bf16* __restrict__ attn, const bf16* __restrict__ wo,
    const float* __restrict__ bo, float* __restrict__ out)
{
  __shared__ bf16 As[128 * 32];
  __shared__ bf16 Bs[128 * 32];
  const int m0 = blockIdx.x * 128, n0 = blockIdx.y * 128;

  floatx4 acc[4][4];
  gemm128_core(attn, wo, m0, n0, As, Bs, acc);

  const int t = threadIdx.x, l = t & 63, w = t >> 6;
  const int quad = l >> 4, lr = l & 15;
  const int wm = (w >> 1) * 64, wn = (w & 1) * 64;

#pragma unroll
  for (int i = 0; i < 4; i++) {
    int m = m0 + wm + i * 16 + quad * 4;
#pragma unroll
    for (int j = 0; j < 4; j++) {
      int n = n0 + wn + j * 16 + lr;
      float bv = bo[n];
      float* p = out + (size_t)m * D_MODEL + n;
#pragma unroll
      for (int r = 0; r < 4; r++)
        p[(size_t)r * D_MODEL] = acc[i][j][r] + bv;
    }
  }
}

// ---------------------------------------------------------------------------
extern "C" void kernel_launch(void* const* d_in, const int* in_sizes, int n_in,
                              void* d_out, int out_size, void* d_ws, size_t ws_size,
                              hipStream_t stream)
{
  const float* q  = (const float*)d_in[0];
  const float* k  = (const float*)d_in[1];
  const float* v  = (const float*)d_in[2];
  const float* Wq = (const float*)d_in[3];
  const float* bq = (const float*)d_in[4];
  const float* Wk = (const float*)d_in[5];
  const float* bk = (const float*)d_in[6];
  const float* Wv = (const float*)d_in[7];
  const float* bv = (const float*)d_in[8];
  const float* Wo = (const float*)d_in[9];
  const float* bo = (const float*)d_in[10];

  const size_t NQ = (size_t)BT * D_MODEL;        // 4194304
  const size_t NW = (size_t)D_MODEL * D_MODEL;   // 1048576

  bf16* p = (bf16*)d_ws;
  bf16* qb   = p; p += NQ;
  bf16* kb   = p; p += NQ;
  bf16* vb   = p; p += NQ;
  bf16* wqb  = p; p += NW;
  bf16* wkb  = p; p += NW;
  bf16* wvb  = p; p += NW;
  bf16* wob  = p; p += NW;
  bf16* qhp  = p; p += NQ;   // [B*H][T][64]
  bf16* khp  = p; p += NQ;   // [B*H][T][64]
  bf16* vtp  = p; p += NQ;   // [B*H][64][T]
  bf16* attn = p; p += NQ;   // [B][T][1024]

  cvt7<<<dim3(1024, 7, 1), 256, 0, stream>>>(q, k, v, Wq, Wk, Wv, Wo,
                                             qb, kb, vb, wqb, wkb, wvb, wob);
  qkv_gemm<<<dim3(32, 8, 3), 256, 0, stream>>>(qb, kb, vb, wqb, wkb, wvb,
                                               bq, bk, bv, qhp, khp, vtp);
  attn_fused<<<dim3(16, 32, 1), 512, 0, stream>>>(qhp, khp, vtp, attn);
  oproj_gemm<<<dim3(32, 8, 1), 256, 0, stream>>>(attn, wob, bo, (float*)d_out);
}